// Round 2
// baseline (275.398 us; speedup 1.0000x reference)
//
#include <hip/hip_runtime.h>

#define QMIN_V 0.1f
#define EPS_V  1e-7f

// ---------------------------------------------------------------------------
// ws layout: [ u64 packed[np] | float4 maxdata[np] | float accum[nn] ]
// packed[p] = (bits(beta_mail) << 32) | edge_idx  -- lexicographic argmax
// ---------------------------------------------------------------------------

__global__ void init_ws_kernel(unsigned long long* __restrict__ packed,
                               float* __restrict__ accum, int np, int nn) {
    int tid = blockIdx.x * blockDim.x + threadIdx.x;
    int stride = gridDim.x * blockDim.x;
    for (int j = tid; j < np; j += stride) packed[j] = 0ULL;
    for (int j = tid; j < nn; j += stride) accum[j] = 0.0f;
}

// Pass A: per-edge mailbox value -> per-particle packed atomicMax.
// beta_mail > 0 requires label==1 (rare: ~1.8e-4 of edges), so the atomic
// is almost never executed; the common path is 2 coalesced loads + 1 gather.
__global__ void passA_kernel(const int* __restrict__ edge_node,
                             const int* __restrict__ edge_particle,
                             const float* __restrict__ beta,
                             const int* __restrict__ isTrack,
                             const int* __restrict__ parent_target,
                             const int* __restrict__ particle_idx,
                             const int* __restrict__ particle_class,
                             unsigned long long* __restrict__ packed,
                             int ne4, int ne) {
    int tid = blockIdx.x * blockDim.x + threadIdx.x;
    int stride = gridDim.x * blockDim.x;
    for (int i = tid; i < ne4; i += stride) {
        int4 en = reinterpret_cast<const int4*>(edge_node)[i];
        int4 ep = reinterpret_cast<const int4*>(edge_particle)[i];
#pragma unroll
        for (int k = 0; k < 4; ++k) {
            int n = (&en.x)[k];
            int p = (&ep.x)[k];
            int pt = parent_target[n];
            if (pt == particle_idx[p]) {
                float b = beta[n];
                int pc = particle_class[p];
                float bm = (pc < 2) ? b : b * (float)isTrack[n];
                if (bm > 0.0f) {
                    unsigned long long key =
                        ((unsigned long long)__float_as_uint(bm) << 32) |
                        (unsigned int)(i * 4 + k);
                    atomicMax(&packed[p], key);
                }
            }
        }
    }
    // scalar tail (ne not divisible by 4)
    for (int e = ne4 * 4 + tid; e < ne; e += stride) {
        int n = edge_node[e];
        int p = edge_particle[e];
        if (parent_target[n] == particle_idx[p]) {
            float b = beta[n];
            int pc = particle_class[p];
            float bm = (pc < 2) ? b : b * (float)isTrack[n];
            if (bm > 0.0f) {
                unsigned long long key =
                    ((unsigned long long)__float_as_uint(bm) << 32) |
                    (unsigned int)e;
                atomicMax(&packed[p], key);
            }
        }
    }
}

// Pass P: unpack winner edge per particle, emit (max_q, max_x) payload.
__global__ void passP_kernel(const unsigned long long* __restrict__ packed,
                             const int* __restrict__ edge_node,
                             const float* __restrict__ beta,
                             const float* __restrict__ x,
                             float4* __restrict__ maxdata, int np) {
    int p = blockIdx.x * blockDim.x + threadIdx.x;
    if (p >= np) return;
    unsigned long long key = packed[p];
    unsigned int bm_bits = (unsigned int)(key >> 32);
    float4 md = make_float4(0.0f, 0.0f, 0.0f, 0.0f);
    if (bm_bits != 0u) {   // valid <=> max beta_mail > 0 (matches reference)
        int e = (int)(key & 0xffffffffULL);
        int n = edge_node[e];
        float b = beta[n];
        float cb = fminf(fmaxf(b, EPS_V), 1.0f - EPS_V);
        float a = atanhf(cb);
        md.x = a * a + QMIN_V;       // max_q  (label==1 at winner edge)
        md.y = x[3 * n + 0];
        md.z = x[3 * n + 1];
        md.w = x[3 * n + 2];
    }
    maxdata[p] = md;
}

// Pass B: per-edge potential -> atomicAdd into node accumulator.
// v == 0 whenever mq == 0 (~70% of particles) or (label==0 && dist>=2),
// so most edges skip the atomic.
__global__ void passB_kernel(const int* __restrict__ edge_node,
                             const int* __restrict__ edge_particle,
                             const float* __restrict__ x,
                             const int* __restrict__ parent_target,
                             const int* __restrict__ particle_idx,
                             const float4* __restrict__ maxdata,
                             float* __restrict__ accum,
                             int ne4, int ne) {
    int tid = blockIdx.x * blockDim.x + threadIdx.x;
    int stride = gridDim.x * blockDim.x;
    for (int i = tid; i < ne4; i += stride) {
        int4 en = reinterpret_cast<const int4*>(edge_node)[i];
        int4 ep = reinterpret_cast<const int4*>(edge_particle)[i];
#pragma unroll
        for (int k = 0; k < 4; ++k) {
            int n = (&en.x)[k];
            int p = (&ep.x)[k];
            float4 md = maxdata[p];
            float mq = md.x;
            if (mq > 0.0f) {
                float dx = md.y - x[3 * n + 0];
                float dy = md.z - x[3 * n + 1];
                float dz = md.w - x[3 * n + 2];
                float dist = sqrtf(dx * dx + dy * dy + dz * dz);
                bool label = (parent_target[n] == particle_idx[p]);
                float v = label ? (3.0f * mq * dist * dist)
                                : (fmaxf(2.0f - dist, 0.0f) * mq);
                if (v != 0.0f) atomicAdd(&accum[n], v);
            }
        }
    }
    for (int e = ne4 * 4 + tid; e < ne; e += stride) {
        int n = edge_node[e];
        int p = edge_particle[e];
        float4 md = maxdata[p];
        float mq = md.x;
        if (mq > 0.0f) {
            float dx = md.y - x[3 * n + 0];
            float dy = md.z - x[3 * n + 1];
            float dz = md.w - x[3 * n + 2];
            float dist = sqrtf(dx * dx + dy * dy + dz * dz);
            bool label = (parent_target[n] == particle_idx[p]);
            float v = label ? (3.0f * mq * dist * dist)
                            : (fmaxf(2.0f - dist, 0.0f) * mq);
            if (v != 0.0f) atomicAdd(&accum[n], v);
        }
    }
}

// Pass N: node_lv = q * (attract + repulse)
__global__ void passN_kernel(const float* __restrict__ beta,
                             const float* __restrict__ accum,
                             float* __restrict__ out, int nn) {
    int i = blockIdx.x * blockDim.x + threadIdx.x;
    if (i >= nn) return;
    float b = beta[i];
    float cb = fminf(fmaxf(b, EPS_V), 1.0f - EPS_V);
    float a = atanhf(cb);
    out[i] = (a * a + QMIN_V) * accum[i];
}

extern "C" void kernel_launch(void* const* d_in, const int* in_sizes, int n_in,
                              void* d_out, int out_size, void* d_ws, size_t ws_size,
                              hipStream_t stream) {
    const float* beta           = (const float*)d_in[0];
    const float* x              = (const float*)d_in[1];
    const int*   isTrack        = (const int*)d_in[2];
    const int*   parent_target  = (const int*)d_in[3];
    const int*   particle_idx   = (const int*)d_in[4];
    const int*   particle_class = (const int*)d_in[5];
    const int*   edge_node      = (const int*)d_in[6];
    const int*   edge_particle  = (const int*)d_in[7];
    float* out = (float*)d_out;

    int nn = in_sizes[0];
    int np = in_sizes[4];
    int ne = in_sizes[6];

    char* ws = (char*)d_ws;
    unsigned long long* packed = (unsigned long long*)ws;          // np * 8 B
    size_t off1 = ((size_t)np * 8 + 15) & ~(size_t)15;
    float4* maxdata = (float4*)(ws + off1);                        // np * 16 B
    size_t off2 = off1 + (size_t)np * 16;
    float* accum = (float*)(ws + off2);                            // nn * 4 B

    int ne4 = ne / 4;

    init_ws_kernel<<<256, 256, 0, stream>>>(packed, accum, np, nn);
    passA_kernel<<<2048, 256, 0, stream>>>(edge_node, edge_particle, beta,
                                           isTrack, parent_target, particle_idx,
                                           particle_class, packed, ne4, ne);
    passP_kernel<<<(np + 255) / 256, 256, 0, stream>>>(packed, edge_node, beta,
                                                       x, maxdata, np);
    passB_kernel<<<2048, 256, 0, stream>>>(edge_node, edge_particle, x,
                                           parent_target, particle_idx,
                                           maxdata, accum, ne4, ne);
    passN_kernel<<<(nn + 255) / 256, 256, 0, stream>>>(beta, accum, out, nn);
}

// Round 4
// 233.488 us; speedup vs baseline: 1.1795x; 1.1795x over previous
//
#include <hip/hip_runtime.h>

#define QMIN_V 0.1f
#define EPS_V  1e-7f

// ---------------------------------------------------------------------------
// ws layout (all 16B-aligned):
//   float4 maxdata[np]   (mx,my,mz, bitcast(pidx))
//   float4 xpt[nn]       (x0,x1,x2, bitcast(parent_target))   [optional]
//   u64    packed[np]    (bits(beta_mail)<<32 | edge_idx)
//   float  mq[np]
//   float  accum[nn]
// ---------------------------------------------------------------------------

__global__ void init_ws_kernel(unsigned long long* __restrict__ packed,
                               float* __restrict__ accum, int np, int nn) {
    int tid = blockIdx.x * blockDim.x + threadIdx.x;
    int stride = gridDim.x * blockDim.x;
    for (int j = tid; j < np; j += stride) packed[j] = 0ULL;
    for (int j = tid; j < nn; j += stride) accum[j] = 0.0f;
}

__global__ void prep_xpt_kernel(const float* __restrict__ x,
                                const int* __restrict__ pt,
                                float4* __restrict__ xpt, int nn) {
    int i = blockIdx.x * blockDim.x + threadIdx.x;
    if (i >= nn) return;
    xpt[i] = make_float4(x[3 * i + 0], x[3 * i + 1], x[3 * i + 2],
                         __int_as_float(pt[i]));
}

// Pass A: per-edge label -> per-particle packed atomicMax (rare).
// Batched U=8: 8 independent pt gathers in flight, pidx from LDS.
__global__ void passA_kernel(const int* __restrict__ edge_node,
                             const int* __restrict__ edge_particle,
                             const float* __restrict__ beta,
                             const int* __restrict__ isTrack,
                             const int* __restrict__ pt,
                             const int* __restrict__ pidx,
                             const int* __restrict__ pclass,
                             unsigned long long* __restrict__ packed,
                             int np, int ne8, int ne) {
    extern __shared__ int s_pidx[];
    for (int j = threadIdx.x; j < np; j += blockDim.x) s_pidx[j] = pidx[j];
    __syncthreads();

    int tid = blockIdx.x * blockDim.x + threadIdx.x;
    int stride = gridDim.x * blockDim.x;
    const int4* en4 = reinterpret_cast<const int4*>(edge_node);
    const int4* ep4 = reinterpret_cast<const int4*>(edge_particle);

    for (int i = tid; i < ne8; i += stride) {
        int4 a0 = en4[2 * i], a1 = en4[2 * i + 1];
        int4 b0 = ep4[2 * i], b1 = ep4[2 * i + 1];
        int n[8] = {a0.x, a0.y, a0.z, a0.w, a1.x, a1.y, a1.z, a1.w};
        int p[8] = {b0.x, b0.y, b0.z, b0.w, b1.x, b1.y, b1.z, b1.w};
        int t[8];
#pragma unroll
        for (int k = 0; k < 8; ++k) t[k] = pt[n[k]];       // batched gathers
        int q[8];
#pragma unroll
        for (int k = 0; k < 8; ++k) q[k] = s_pidx[p[k]];   // LDS reads
#pragma unroll
        for (int k = 0; k < 8; ++k) {
            if (t[k] == q[k]) {                             // ~1.8e-4 density
                float b = beta[n[k]];
                int pc = pclass[p[k]];
                float bm = (pc < 2) ? b : b * (float)isTrack[n[k]];
                if (bm > 0.0f) {
                    unsigned long long key =
                        ((unsigned long long)__float_as_uint(bm) << 32) |
                        (unsigned int)(8 * i + k);
                    atomicMax(&packed[p[k]], key);
                }
            }
        }
    }
    // scalar tail
    for (int e = ne8 * 8 + tid; e < ne; e += stride) {
        int n = edge_node[e];
        int p = edge_particle[e];
        if (pt[n] == pidx[p]) {
            float b = beta[n];
            int pc = pclass[p];
            float bm = (pc < 2) ? b : b * (float)isTrack[n];
            if (bm > 0.0f) {
                unsigned long long key =
                    ((unsigned long long)__float_as_uint(bm) << 32) |
                    (unsigned int)e;
                atomicMax(&packed[p], key);
            }
        }
    }
}

// Pass P: unpack winner, emit per-particle payload.
__global__ void passP_kernel(const unsigned long long* __restrict__ packed,
                             const int* __restrict__ edge_node,
                             const float* __restrict__ beta,
                             const float* __restrict__ x,
                             const int* __restrict__ pidx,
                             float4* __restrict__ maxdata,
                             float* __restrict__ mq, int np) {
    int p = blockIdx.x * blockDim.x + threadIdx.x;
    if (p >= np) return;
    unsigned long long key = packed[p];
    unsigned int bm_bits = (unsigned int)(key >> 32);
    float mqv = 0.0f, mx = 0.0f, my = 0.0f, mz = 0.0f;
    if (bm_bits != 0u) {  // valid <=> max beta_mail > 0
        int e = (int)(key & 0xffffffffULL);
        int n = edge_node[e];
        float b = beta[n];
        float cb = fminf(fmaxf(b, EPS_V), 1.0f - EPS_V);
        float a = atanhf(cb);
        mqv = a * a + QMIN_V;
        mx = x[3 * n + 0];
        my = x[3 * n + 1];
        mz = x[3 * n + 2];
    }
    maxdata[p] = make_float4(mx, my, mz, __int_as_float(pidx[p]));
    mq[p] = mqv;
}

// Pass B: per-edge potential -> atomicAdd into node accumulator.
// mq from LDS (cheap reject, ~78% of edges); active path = 2x 16B gathers.
template <int USE_XPT>
__global__ void passB_kernel(const int* __restrict__ edge_node,
                             const int* __restrict__ edge_particle,
                             const float* __restrict__ x,
                             const int* __restrict__ pt,
                             const float4* __restrict__ xpt,
                             const float4* __restrict__ maxdata,
                             const float* __restrict__ mq,
                             float* __restrict__ accum,
                             int np, int ne4, int ne) {
    extern __shared__ float s_mq[];
    for (int j = threadIdx.x; j < np; j += blockDim.x) s_mq[j] = mq[j];
    __syncthreads();

    int tid = blockIdx.x * blockDim.x + threadIdx.x;
    int stride = gridDim.x * blockDim.x;
    const int4* en4 = reinterpret_cast<const int4*>(edge_node);
    const int4* ep4 = reinterpret_cast<const int4*>(edge_particle);

    for (int i = tid; i < ne4; i += stride) {
        int4 a = en4[i];
        int4 b = ep4[i];
        int n[4] = {a.x, a.y, a.z, a.w};
        int p[4] = {b.x, b.y, b.z, b.w};
        float m[4];
#pragma unroll
        for (int k = 0; k < 4; ++k) m[k] = s_mq[p[k]];
        float4 md[4];
        float xv0[4], xv1[4], xv2[4];
        int ptv[4];
#pragma unroll
        for (int k = 0; k < 4; ++k) {
            if (m[k] > 0.0f) {                      // ~22% density
                md[k] = maxdata[p[k]];
                if (USE_XPT) {
                    float4 xp = xpt[n[k]];
                    xv0[k] = xp.x; xv1[k] = xp.y; xv2[k] = xp.z;
                    ptv[k] = __float_as_int(xp.w);
                } else {
                    xv0[k] = x[3 * n[k] + 0];
                    xv1[k] = x[3 * n[k] + 1];
                    xv2[k] = x[3 * n[k] + 2];
                    ptv[k] = pt[n[k]];
                }
            }
        }
#pragma unroll
        for (int k = 0; k < 4; ++k) {
            if (m[k] > 0.0f) {
                float dx = md[k].x - xv0[k];
                float dy = md[k].y - xv1[k];
                float dz = md[k].z - xv2[k];
                float d2 = dx * dx + dy * dy + dz * dz;
                bool label = (ptv[k] == __float_as_int(md[k].w));
                float v;
                if (label) v = 3.0f * m[k] * d2;            // attract: no sqrt needed
                else       v = fmaxf(2.0f - sqrtf(d2), 0.0f) * m[k];
                if (v != 0.0f) atomicAdd(&accum[n[k]], v);
            }
        }
    }
    // scalar tail
    for (int e = ne4 * 4 + tid; e < ne; e += stride) {
        int n = edge_node[e];
        int p = edge_particle[e];
        float m = s_mq[p];
        if (m > 0.0f) {
            float4 md = maxdata[p];
            float x0, x1, x2; int ptv;
            if (USE_XPT) {
                float4 xp = xpt[n];
                x0 = xp.x; x1 = xp.y; x2 = xp.z; ptv = __float_as_int(xp.w);
            } else {
                x0 = x[3 * n + 0]; x1 = x[3 * n + 1]; x2 = x[3 * n + 2];
                ptv = pt[n];
            }
            float dx = md.x - x0, dy = md.y - x1, dz = md.z - x2;
            float d2 = dx * dx + dy * dy + dz * dz;
            bool label = (ptv == __float_as_int(md.w));
            float v = label ? (3.0f * m * d2)
                            : (fmaxf(2.0f - sqrtf(d2), 0.0f) * m);
            if (v != 0.0f) atomicAdd(&accum[n], v);
        }
    }
}

// Pass N: node_lv = q * (attract + repulse)
__global__ void passN_kernel(const float* __restrict__ beta,
                             const float* __restrict__ accum,
                             float* __restrict__ out, int nn) {
    int i = blockIdx.x * blockDim.x + threadIdx.x;
    if (i >= nn) return;
    float b = beta[i];
    float cb = fminf(fmaxf(b, EPS_V), 1.0f - EPS_V);
    float a = atanhf(cb);
    out[i] = (a * a + QMIN_V) * accum[i];
}

extern "C" void kernel_launch(void* const* d_in, const int* in_sizes, int n_in,
                              void* d_out, int out_size, void* d_ws, size_t ws_size,
                              hipStream_t stream) {
    const float* beta    = (const float*)d_in[0];
    const float* x       = (const float*)d_in[1];
    const int*   isTrack = (const int*)d_in[2];
    const int*   pt      = (const int*)d_in[3];
    const int*   pidx    = (const int*)d_in[4];
    const int*   pclass  = (const int*)d_in[5];
    const int*   en      = (const int*)d_in[6];
    const int*   ep      = (const int*)d_in[7];
    float* out = (float*)d_out;

    int nn = in_sizes[0];
    int np = in_sizes[4];
    int ne = in_sizes[6];

    // ws layout
    char* ws = (char*)d_ws;
    size_t off = 0;
    float4* maxdata = (float4*)(ws + off); off += (size_t)np * 16;
    size_t xpt_off = off;
    size_t need_xpt = off + (size_t)nn * 16 + (size_t)np * 8 + (size_t)np * 4
                      + (size_t)nn * 4;
    bool use_xpt = (ws_size >= need_xpt);
    float4* xpt = nullptr;
    if (use_xpt) { xpt = (float4*)(ws + xpt_off); off += (size_t)nn * 16; }
    unsigned long long* packed = (unsigned long long*)(ws + off); off += (size_t)np * 8;
    float* mq = (float*)(ws + off); off += (size_t)np * 4;
    float* accum = (float*)(ws + off);

    int ne8 = ne / 8;
    int ne4 = ne / 4;
    int lds_bytes = np * (int)sizeof(int);

    init_ws_kernel<<<256, 256, 0, stream>>>(packed, accum, np, nn);
    if (use_xpt)
        prep_xpt_kernel<<<(nn + 255) / 256, 256, 0, stream>>>(x, pt, xpt, nn);
    passA_kernel<<<2048, 256, lds_bytes, stream>>>(en, ep, beta, isTrack, pt,
                                                   pidx, pclass, packed,
                                                   np, ne8, ne);
    passP_kernel<<<(np + 255) / 256, 256, 0, stream>>>(packed, en, beta, x,
                                                       pidx, maxdata, mq, np);
    if (use_xpt)
        passB_kernel<1><<<2048, 256, lds_bytes, stream>>>(en, ep, x, pt, xpt,
                                                          maxdata, mq, accum,
                                                          np, ne4, ne);
    else
        passB_kernel<0><<<2048, 256, lds_bytes, stream>>>(en, ep, x, pt, xpt,
                                                          maxdata, mq, accum,
                                                          np, ne4, ne);
    passN_kernel<<<(nn + 255) / 256, 256, 0, stream>>>(beta, accum, out, nn);
}